// Round 3
// baseline (1284.633 us; speedup 1.0000x reference)
//
#include <hip/hip_runtime.h>

typedef _Float16 f16x8 __attribute__((ext_vector_type(8)));
typedef float f32x4 __attribute__((ext_vector_type(4)));

#define EPS 1e-5f

__device__ __forceinline__ short f2h(float x) {
    _Float16 h = (_Float16)x;   // RNE v_cvt_f16_f32
    union { _Float16 h; short s; } u;
    u.h = h;
    return u.s;
}

// ---------------------------------------------------------------------------
// prep: output-linear transpose+convert. WtM[l][f][k] fp16 <- Wm[l][k][f],
// WtF[f][k] fp16 (f padded to 48), stats zeroed. Coalesced writes; gathered
// reads are L2-absorbed (each 448 KB layer slab is L2-resident).
// ---------------------------------------------------------------------------
__global__ __launch_bounds__(256) void prep_kernel(
        const float* __restrict__ Wm, const float* __restrict__ Wl,
        short* __restrict__ WtM, short* __restrict__ WtF,
        float* __restrict__ stats) {
    const long T1 = 14L * 896 * 128;   // WtM elements (output-linear)
    const long T2 = 48L * 896;         // WtF elements
    const long T3 = 15L * 256;         // stats
    long i = (long)blockIdx.x * blockDim.x + threadIdx.x;
    if (i < T1) {
        long l = i / 114688;
        long r = i % 114688;
        long f = r / 896;
        long k = r % 896;
        WtM[i] = f2h(Wm[l * 114688 + k * 128 + f]);
    } else if (i < T1 + T2) {
        long j = i - T1;
        long f = j / 896;
        long k = j % 896;
        WtF[j] = (f < 36) ? f2h(Wl[k * 36 + f]) : (short)0;
    } else if (i < T1 + T2 + T3) {
        stats[i - T1 - T2] = 0.0f;
    }
}

// ---------------------------------------------------------------------------
// layer0: wave-per-node, barrier-free (except W0 staging). lane covers feats
// (lane, lane+64). W0 (10.5 KB) in LDS; x row loads are wave-uniform (L1 broadcast).
// ---------------------------------------------------------------------------
__global__ __launch_bounds__(256) void layer0_kernel(
        const float* __restrict__ x, const int* __restrict__ idx,
        const float* __restrict__ W0, const float* __restrict__ b0,
        float* __restrict__ hlin, float* __restrict__ stats, int N) {
    __shared__ float sW[21 * 128];
    __shared__ float sstat[256];
    const int tid = threadIdx.x;
    const int lane = tid & 63;
    const int wave = tid >> 6;
    for (int i = tid; i < 21 * 128; i += 256) sW[i] = W0[i];
    sstat[tid] = 0.f;
    __syncthreads();

    const int f0 = lane, f1 = lane + 64;
    const float bb0 = b0[f0], bb1 = b0[f1];
    float s0 = 0.f, ss0 = 0.f, s1 = 0.f, ss1 = 0.f;

    const int gw = blockIdx.x * 4 + wave;
    const int nw = gridDim.x * 4;
    for (int n = gw; n < N; n += nw) {
        float a0 = bb0, a1 = bb1;
#pragma unroll
        for (int j = 0; j < 7; ++j) {
            int r = idx[n * 7 + j];
            float x0 = x[(long)r * 3 + 0];
            float x1 = x[(long)r * 3 + 1];
            float x2 = x[(long)r * 3 + 2];
            int k = j * 3;
            a0 = fmaf(x0, sW[(k + 0) * 128 + f0], a0);
            a0 = fmaf(x1, sW[(k + 1) * 128 + f0], a0);
            a0 = fmaf(x2, sW[(k + 2) * 128 + f0], a0);
            a1 = fmaf(x0, sW[(k + 0) * 128 + f1], a1);
            a1 = fmaf(x1, sW[(k + 1) * 128 + f1], a1);
            a1 = fmaf(x2, sW[(k + 2) * 128 + f1], a1);
        }
        hlin[(long)n * 128 + f0] = a0;
        hlin[(long)n * 128 + f1] = a1;
        s0 += a0; ss0 += a0 * a0;
        s1 += a1; ss1 += a1 * a1;
    }
    atomicAdd(&sstat[f0], s0);
    atomicAdd(&sstat[128 + f0], ss0);
    atomicAdd(&sstat[f1], s1);
    atomicAdd(&sstat[128 + f1], ss1);
    __syncthreads();
    if (tid < 256) atomicAdd(&stats[tid], sstat[tid]);
}

// ---------------------------------------------------------------------------
// bn_relu: h_out_fp16 = relu(scale[f]*h_lin + shift[f]), scale/shift folded
// from stats. HBM/L3-bound streaming pass.
// ---------------------------------------------------------------------------
__global__ __launch_bounds__(256) void bn_relu_kernel(
        const float* __restrict__ hlin, const float* __restrict__ stats,
        const float* __restrict__ g, const float* __restrict__ be,
        unsigned short* __restrict__ hout, int total4, float invN) {
    __shared__ float sSc[128], sSh[128];
    const int tid = threadIdx.x;
    if (tid < 128) {
        float mu = stats[tid] * invN;
        float var = stats[128 + tid] * invN - mu * mu;
        float rs = rsqrtf(var + EPS);
        float sc = g[tid] * rs;
        sSc[tid] = sc;
        sSh[tid] = be[tid] - mu * sc;
    }
    __syncthreads();
    for (int i = blockIdx.x * blockDim.x + tid; i < total4; i += gridDim.x * blockDim.x) {
        long base = (long)i * 4;
        int f0 = (int)(base & 127);
        float4 v = *(const float4*)&hlin[base];
        float y0 = fmaxf(fmaf(v.x, sSc[f0 + 0], sSh[f0 + 0]), 0.f);
        float y1 = fmaxf(fmaf(v.y, sSc[f0 + 1], sSh[f0 + 1]), 0.f);
        float y2 = fmaxf(fmaf(v.z, sSc[f0 + 2], sSh[f0 + 2]), 0.f);
        float y3 = fmaxf(fmaf(v.w, sSc[f0 + 3], sSh[f0 + 3]), 0.f);
        uint2 o;
        o.x = (unsigned)(unsigned short)f2h(y0) | ((unsigned)(unsigned short)f2h(y1) << 16);
        o.y = (unsigned)(unsigned short)f2h(y2) | ((unsigned)(unsigned short)f2h(y3) << 16);
        *(uint2*)&hout[base] = o;
    }
}

// ---------------------------------------------------------------------------
// gemm_mid v2: STREAMING, zero LDS staging, zero barriers in the K-loop.
// h_lin[N,128] = gather7(h_fp16)[N,896] @ W[896,128] + b, plus per-feature stats.
// Block 256 = 4 waves; wave = 32 nodes (wm) x 64 feats (wf); block tile 64x128.
// A-frag: 16 B of gathered node row (L2/L3-hot). B-frag: 16 B of Wt row
// (L2-hot, 4 quads of a 16-lane group cover one full 64 B line).
// idx prefetched one j ahead to hide the dependent gather.
// ---------------------------------------------------------------------------
__global__ __launch_bounds__(256, 4) void gemm_mid_kernel(
        const short* __restrict__ hin, const int* __restrict__ idx,
        const short* __restrict__ Wt, const float* __restrict__ bvec,
        float* __restrict__ hlin, float* __restrict__ stats, int N) {
    __shared__ float sstat[256];

    const int tid = threadIdx.x;
    const int wave = tid >> 6;
    const int lane = tid & 63;
    const int quad = lane >> 4;
    const int l16 = lane & 15;
    const int wm = wave & 1;        // node half (32 nodes)
    const int wf = wave >> 1;       // feat half (64 feats)
    const int m0 = blockIdx.x * 64;

    sstat[tid] = 0.f;
    __syncthreads();

    // this lane's two node rows (mi=0,1), clamped for loads
    const int n0 = m0 + wm * 32 + l16;
    const int n1 = n0 + 16;
    const int c0 = (n0 < N) ? n0 : (N - 1);
    const int c1 = (n1 < N) ? n1 : (N - 1);
    const int fb = wf * 64 + l16;   // this lane's base feat row in Wt

    f32x4 acc[2][4];
#pragma unroll
    for (int ni = 0; ni < 4; ++ni) {
        float bv = bvec[fb + ni * 16];
        acc[0][ni][0] = bv; acc[0][ni][1] = bv; acc[0][ni][2] = bv; acc[0][ni][3] = bv;
        acc[1][ni][0] = bv; acc[1][ni][1] = bv; acc[1][ni][2] = bv; acc[1][ni][3] = bv;
    }

    int r0 = idx[c0 * 7 + 0];
    int r1 = idx[c1 * 7 + 0];
#pragma unroll 1
    for (int j = 0; j < 7; ++j) {
        const short* a0p = hin + (long)r0 * 128;
        const short* a1p = hin + (long)r1 * 128;
        if (j < 6) {                      // prefetch next gather indices
            r0 = idx[c0 * 7 + j + 1];
            r1 = idx[c1 * 7 + j + 1];
        }
        const short* bp = Wt + (long)fb * 896 + j * 128 + quad * 8;
#pragma unroll
        for (int k0 = 0; k0 < 128; k0 += 32) {
            f16x8 a0 = *(const f16x8*)(a0p + k0 + quad * 8);
            f16x8 a1 = *(const f16x8*)(a1p + k0 + quad * 8);
            f16x8 b[4];
#pragma unroll
            for (int ni = 0; ni < 4; ++ni)
                b[ni] = *(const f16x8*)(bp + (long)ni * 16 * 896 + k0);
#pragma unroll
            for (int ni = 0; ni < 4; ++ni) {
                acc[0][ni] = __builtin_amdgcn_mfma_f32_16x16x32_f16(a0, b[ni], acc[0][ni], 0, 0, 0);
                acc[1][ni] = __builtin_amdgcn_mfma_f32_16x16x32_f16(a1, b[ni], acc[1][ni], 0, 0, 0);
            }
        }
    }

    // epilogue: store h_lin fp32 + per-feature stats (LDS then one global atomic)
#pragma unroll
    for (int mi = 0; mi < 2; ++mi) {
#pragma unroll
        for (int ni = 0; ni < 4; ++ni) {
            int feat = wf * 64 + ni * 16 + l16;
            float s = 0.f, ss = 0.f;
#pragma unroll
            for (int r = 0; r < 4; ++r) {
                int node = m0 + wm * 32 + mi * 16 + quad * 4 + r;
                float v = acc[mi][ni][r];
                if (node < N) {
                    hlin[(long)node * 128 + feat] = v;
                    s += v;
                    ss += v * v;
                }
            }
            atomicAdd(&sstat[feat], s);
            atomicAdd(&sstat[128 + feat], ss);
        }
    }
    __syncthreads();
    if (tid < 128) {
        atomicAdd(&stats[tid], sstat[tid]);
        atomicAdd(&stats[128 + tid], sstat[128 + tid]);
    }
}

// ---------------------------------------------------------------------------
// gemm_final v2: streaming, no LDS. out[N,36] = gather7(h)[N,896]@Wl + bl.
// Block 256 = 4 waves; wave = 16 nodes x 48 feats (3 ni tiles); block = 64 nodes.
// ---------------------------------------------------------------------------
__global__ __launch_bounds__(256, 4) void gemm_final_kernel(
        const short* __restrict__ hin, const int* __restrict__ idx,
        const short* __restrict__ WtF, const float* __restrict__ bl,
        float* __restrict__ out, int N) {
    const int tid = threadIdx.x;
    const int wave = tid >> 6;
    const int lane = tid & 63;
    const int quad = lane >> 4;
    const int l16 = lane & 15;
    const int m0 = blockIdx.x * 64;

    const int n0 = m0 + wave * 16 + l16;
    const int c0 = (n0 < N) ? n0 : (N - 1);

    f32x4 acc[3];
#pragma unroll
    for (int ni = 0; ni < 3; ++ni) {
        int feat = ni * 16 + l16;
        float bv = (feat < 36) ? bl[feat] : 0.f;
        acc[ni][0] = bv; acc[ni][1] = bv; acc[ni][2] = bv; acc[ni][3] = bv;
    }

    int r0 = idx[c0 * 7 + 0];
#pragma unroll 1
    for (int j = 0; j < 7; ++j) {
        const short* a0p = hin + (long)r0 * 128;
        if (j < 6) r0 = idx[c0 * 7 + j + 1];
        const short* bp = WtF + (long)l16 * 896 + j * 128 + quad * 8;
#pragma unroll
        for (int k0 = 0; k0 < 128; k0 += 32) {
            f16x8 a = *(const f16x8*)(a0p + k0 + quad * 8);
            f16x8 b[3];
#pragma unroll
            for (int ni = 0; ni < 3; ++ni)
                b[ni] = *(const f16x8*)(bp + (long)ni * 16 * 896 + k0);
#pragma unroll
            for (int ni = 0; ni < 3; ++ni)
                acc[ni] = __builtin_amdgcn_mfma_f32_16x16x32_f16(a, b[ni], acc[ni], 0, 0, 0);
        }
    }

#pragma unroll
    for (int ni = 0; ni < 3; ++ni) {
        int feat = ni * 16 + l16;
        if (feat < 36) {
#pragma unroll
            for (int r = 0; r < 4; ++r) {
                int node = m0 + wave * 16 + quad * 4 + r;
                if (node < N) out[(long)node * 36 + feat] = acc[ni][r];
            }
        }
    }
}

// ---------------------------------------------------------------------------
extern "C" void kernel_launch(void* const* d_in, const int* in_sizes, int n_in,
                              void* d_out, int out_size, void* d_ws, size_t ws_size,
                              hipStream_t stream) {
    const float* x   = (const float*)d_in[0];
    const int*   idx = (const int*)d_in[1];
    const float* W0  = (const float*)d_in[2];
    const float* b0  = (const float*)d_in[3];
    const float* g0  = (const float*)d_in[4];
    const float* be0 = (const float*)d_in[5];
    const float* Wm  = (const float*)d_in[6];
    const float* bm  = (const float*)d_in[7];
    const float* gm  = (const float*)d_in[8];
    const float* bem = (const float*)d_in[9];
    const float* Wl  = (const float*)d_in[10];
    const float* bl  = (const float*)d_in[11];
    float* out = (float*)d_out;

    const int N = in_sizes[0] / 3;          // 40962
    const float invN = 1.0f / (float)N;

    char* ws = (char*)d_ws;
    size_t off = 0;
    auto alloc = [&](size_t bytes) -> void* {
        void* p = ws + off;
        off = (off + bytes + 255) & ~(size_t)255;
        return p;
    };
    short* WtM   = (short*)alloc(14UL * 128 * 896 * 2);
    short* WtF   = (short*)alloc(48UL * 896 * 2);
    float* stats = (float*)alloc(15UL * 256 * 4);
    float* hlin  = (float*)alloc((size_t)N * 128 * 4);
    short* hA    = (short*)alloc((size_t)N * 128 * 2);
    short* hB    = (short*)alloc((size_t)N * 128 * 2);

    {
        long total = 14L * 896 * 128 + 48L * 896 + 15L * 256;
        int blocks = (int)((total + 255) / 256);
        prep_kernel<<<blocks, 256, 0, stream>>>(Wm, Wl, WtM, WtF, stats);
    }

    layer0_kernel<<<256, 256, 0, stream>>>(x, idx, W0, b0, hlin, stats, N);

    int total4 = N * 32;  // N*128/4
    bn_relu_kernel<<<1024, 256, 0, stream>>>(hlin, stats, g0, be0,
                                             (unsigned short*)hA, total4, invN);

    const int gblocks = (N + 63) / 64;
    short* hin = hA;
    short* hout = hB;
    for (int L = 0; L < 14; ++L) {
        gemm_mid_kernel<<<gblocks, 256, 0, stream>>>(
            hin, idx, WtM + (size_t)L * 128 * 896, bm + L * 128,
            hlin, stats + (L + 1) * 256, N);
        bn_relu_kernel<<<1024, 256, 0, stream>>>(
            hlin, stats + (L + 1) * 256, gm + L * 128, bem + L * 128,
            (unsigned short*)hout, total4, invN);
        short* t = hin; hin = hout; hout = t;
    }

    gemm_final_kernel<<<gblocks, 256, 0, stream>>>(hin, idx, WtF, bl, out, N);
}